// Round 7
// baseline (490.893 us; speedup 1.0000x reference)
//
#include <hip/hip_runtime.h>
#include <hip/hip_bf16.h>

#define N_NODES 100000
#define N_EDGES 1000000
#define S_DIM 64
#define F_DIM 64
#define RBF_DIM 16
#define V_CH 16

typedef __attribute__((ext_vector_type(4))) float f32x4;
typedef __attribute__((ext_vector_type(8))) short bf16x8;

#define NBLK 128
#define TPW 5            // tiles per wave
#define EDGE_GRID 3125   // 3125 * 4 waves * 5 tiles * 16 edges = 1,000,000 exactly

// compiler-level memory barrier: LDS same-wave producer/consumer ordering
#define LDS_FENCE() asm volatile("" ::: "memory")

__device__ __forceinline__ float silu_f(float x) {
    return x * (1.0f / (1.0f + __expf(-x)));
}

__device__ __forceinline__ ushort f2bf(float x) {
    union { __hip_bfloat16 b; ushort u; } c;
    c.b = __float2bfloat16(x);
    return c.u;
}

__device__ __forceinline__ float4 ld4(const float* p) {
    return *reinterpret_cast<const float4*>(p);
}

__device__ __forceinline__ bf16x8 pack8(float4 u, float4 v) {
    bf16x8 r;
    r[0] = (short)f2bf(u.x); r[1] = (short)f2bf(u.y);
    r[2] = (short)f2bf(u.z); r[3] = (short)f2bf(u.w);
    r[4] = (short)f2bf(v.x); r[5] = (short)f2bf(v.y);
    r[6] = (short)f2bf(v.z); r[7] = (short)f2bf(v.w);
    return r;
}

struct Raw { float4 v[14]; };

// ---------------- Edge kernel (MFMA bf16; 3 blocks/CU; shared f32 LDS scratch) --------------
// Per wave: 16-edge x 64-out tile. A-frag: row=lane&15, k=(lane>>4)*8+j.
// C/D: col=lane&15 (+16*nn), row=4*(lane>>4)+reg  [m89-verified layout].
__global__ __launch_bounds__(256, 3) void edge_kernel(
    const float* __restrict__ ns, const float* __restrict__ ef,
    const float* __restrict__ dd, const int* __restrict__ src,
    const int* __restrict__ dst, const float* __restrict__ W1,
    const float* __restrict__ b1, const float* __restrict__ W2,
    const float* __restrict__ b2, const float* __restrict__ lng,
    const float* __restrict__ lnb, float* __restrict__ out)
{
    __shared__ __align__(16) ushort b1f[7][4][64][8];   // 28672 B (W1 frags, write-once)
    __shared__ __align__(16) float  hb[4][16][68];      // 17408 B (per-wave scratch, BOTH round trips)
    // total 46080 B -> 3 blocks/CU

    const int tid  = threadIdx.x;
    const int lane = tid & 63;
    const int wid  = tid >> 6;
    const int l15  = lane & 15;
    const int g    = lane >> 4;

    // ---- one-time W1 swizzle to LDS (bf16x8 both sides; sealed by syncthreads) ----
    {
        const int fl  = tid & 63;
        const int fnn = tid >> 6;
        const int col = 16 * fnn + (fl & 15);
        const int krow = (fl >> 4) << 3;
        #pragma unroll
        for (int kk = 0; kk < 7; ++kk) {
            const int k0 = 32 * kk + krow;
            bf16x8 w;
            #pragma unroll
            for (int j = 0; j < 8; ++j) {
                const int k = k0 + j;
                w[j] = (k < 208) ? (short)f2bf(W1[k * 64 + col]) : (short)0;
            }
            *reinterpret_cast<bf16x8*>(&b1f[kk][fnn][fl][0]) = w;
        }
    }
    __syncthreads();

    // ---- W2 fragments straight from global into registers (one-time, L2-hot) ----
    bf16x8 w2r[2][4];
    #pragma unroll
    for (int kk = 0; kk < 2; ++kk)
        #pragma unroll
        for (int nn = 0; nn < 4; ++nn)
            #pragma unroll
            for (int j = 0; j < 8; ++j)
                w2r[kk][nn][j] = (short)f2bf(W2[(32 * kk + 8 * g + j) * 64 + 16 * nn + l15]);

    float b1c[4], b2c[4];
    #pragma unroll
    for (int nn = 0; nn < 4; ++nn) {
        b1c[nn] = b1[16 * nn + l15];
        b2c[nn] = b2[16 * nn + l15];
    }
    const float4 lgq = ld4(lng + 4 * l15);   // LN gamma/beta in store layout (cols 4*l15..+3)
    const float4 lbq = ld4(lnb + 4 * l15);

    const int wtile0 = (blockIdx.x * 4 + wid) * TPW;

    int sis[TPW], dis[TPW];
    #pragma unroll
    for (int t = 0; t < TPW; ++t) {
        const int erow = (wtile0 + t) * 16 + l15;
        sis[t] = src[erow];
        dis[t] = dst[erow];
    }

    float (*hbw)[68] = hb[wid];

    auto load_raw = [&](Raw& r, int t) {
        const int erow = (wtile0 + t) * 16 + l15;
        const float* ps = ns + (size_t)sis[t] * 64 + 8 * g;
        const float* pd = ns + (size_t)dis[t] * 64 + 8 * g;
        const float* pe = ef + (size_t)erow * 64 + 8 * g;
        const float* pr = dd + (size_t)erow * 16 + 8 * g;
        r.v[0] = ld4(ps);       r.v[1] = ld4(ps + 4);
        r.v[2] = ld4(ps + 32);  r.v[3] = ld4(ps + 36);
        r.v[4] = ld4(pd);       r.v[5] = ld4(pd + 4);
        r.v[6] = ld4(pd + 32);  r.v[7] = ld4(pd + 36);
        r.v[8] = ld4(pe);       r.v[9] = ld4(pe + 4);
        r.v[10] = ld4(pe + 32); r.v[11] = ld4(pe + 36);
        if (g < 2) { r.v[12] = ld4(pr); r.v[13] = ld4(pr + 4); }
        else { r.v[12] = make_float4(0.f,0.f,0.f,0.f); r.v[13] = make_float4(0.f,0.f,0.f,0.f); }
    };

    Raw r;
    load_raw(r, 0);

    #pragma unroll
    for (int t = 0; t < TPW; ++t) {
        const int ebase = (wtile0 + t) * 16;

        // ---- pack A-frags (consumes r; r is dead afterwards) ----
        bf16x8 a0 = pack8(r.v[0], r.v[1]);
        bf16x8 a1 = pack8(r.v[2], r.v[3]);
        bf16x8 a2f = pack8(r.v[4], r.v[5]);
        bf16x8 a3 = pack8(r.v[6], r.v[7]);
        bf16x8 a4 = pack8(r.v[8], r.v[9]);
        bf16x8 a5 = pack8(r.v[10], r.v[11]);
        bf16x8 a6 = pack8(r.v[12], r.v[13]);

        // ---- issue next tile's loads now (WAR on r; compute below hides them) ----
        if (t < TPW - 1) load_raw(r, t + 1);

        // ---- layer 1: frags from LDS (write-once array, no hazard) ----
        f32x4 acc[4];
        #pragma unroll
        for (int nn = 0; nn < 4; ++nn) acc[nn] = (f32x4){0.f, 0.f, 0.f, 0.f};
        #pragma unroll
        for (int nn = 0; nn < 4; ++nn) {
            acc[nn] = __builtin_amdgcn_mfma_f32_16x16x32_bf16(a0, *reinterpret_cast<const bf16x8*>(&b1f[0][nn][lane][0]), acc[nn], 0, 0, 0);
            acc[nn] = __builtin_amdgcn_mfma_f32_16x16x32_bf16(a1, *reinterpret_cast<const bf16x8*>(&b1f[1][nn][lane][0]), acc[nn], 0, 0, 0);
            acc[nn] = __builtin_amdgcn_mfma_f32_16x16x32_bf16(a2f, *reinterpret_cast<const bf16x8*>(&b1f[2][nn][lane][0]), acc[nn], 0, 0, 0);
            acc[nn] = __builtin_amdgcn_mfma_f32_16x16x32_bf16(a3, *reinterpret_cast<const bf16x8*>(&b1f[3][nn][lane][0]), acc[nn], 0, 0, 0);
            acc[nn] = __builtin_amdgcn_mfma_f32_16x16x32_bf16(a4, *reinterpret_cast<const bf16x8*>(&b1f[4][nn][lane][0]), acc[nn], 0, 0, 0);
            acc[nn] = __builtin_amdgcn_mfma_f32_16x16x32_bf16(a5, *reinterpret_cast<const bf16x8*>(&b1f[5][nn][lane][0]), acc[nn], 0, 0, 0);
            acc[nn] = __builtin_amdgcn_mfma_f32_16x16x32_bf16(a6, *reinterpret_cast<const bf16x8*>(&b1f[6][nn][lane][0]), acc[nn], 0, 0, 0);
        }

        // ---- round trip 1 (shared hb, f32): h2 C-layout -> A-layout ----
        LDS_FENCE();   // WAR vs previous tile's round-trip-2 reads
        #pragma unroll
        for (int nn = 0; nn < 4; ++nn)
            #pragma unroll
            for (int rr = 0; rr < 4; ++rr)
                hbw[4 * g + rr][16 * nn + l15] = silu_f(acc[nn][rr] + b1c[nn]);
        LDS_FENCE();   // RAW
        bf16x8 q0, q1;
        #pragma unroll
        for (int j = 0; j < 8; ++j) {
            q0[j] = (short)f2bf(hbw[l15][8 * g + j]);
            q1[j] = (short)f2bf(hbw[l15][32 + 8 * g + j]);
        }

        // ---- layer 2 (weights in registers) ----
        f32x4 acc2[4];
        #pragma unroll
        for (int nn = 0; nn < 4; ++nn) acc2[nn] = (f32x4){0.f, 0.f, 0.f, 0.f};
        #pragma unroll
        for (int nn = 0; nn < 4; ++nn) {
            acc2[nn] = __builtin_amdgcn_mfma_f32_16x16x32_bf16(q0, w2r[0][nn], acc2[nn], 0, 0, 0);
            acc2[nn] = __builtin_amdgcn_mfma_f32_16x16x32_bf16(q1, w2r[1][nn], acc2[nn], 0, 0, 0);
        }

        // ---- round trip 2 (shared hb, f32): silu(acc2)+b2 C-layout -> row-quad layout ----
        LDS_FENCE();   // WAR vs round-trip-1 reads above
        #pragma unroll
        for (int nn = 0; nn < 4; ++nn)
            #pragma unroll
            for (int rr = 0; rr < 4; ++rr)
                hbw[4 * g + rr][16 * nn + l15] = silu_f(acc2[nn][rr] + b2c[nn]);
        LDS_FENCE();   // RAW

        // lane now owns rows (4j+g), cols 4*l15..4*l15+3
        float x[4][4];
        #pragma unroll
        for (int j = 0; j < 4; ++j) {
            const float* hr = &hbw[4 * j + g][4 * l15];
            const float4 e = ld4(ef + (size_t)(ebase + 4 * j + g) * 64 + 4 * l15);  // L1/L2-hot
            x[j][0] = hr[0] + e.x;
            x[j][1] = hr[1] + e.y;
            x[j][2] = hr[2] + e.z;
            x[j][3] = hr[3] + e.w;
        }

        // ---- layernorm: row = 16-lane group sharing g ----
        #pragma unroll
        for (int j = 0; j < 4; ++j) {
            float s = x[j][0] + x[j][1] + x[j][2] + x[j][3];
            s += __shfl_xor(s, 1); s += __shfl_xor(s, 2);
            s += __shfl_xor(s, 4); s += __shfl_xor(s, 8);
            const float mean = s * (1.0f / 64.0f);
            float v = 0.f;
            #pragma unroll
            for (int c = 0; c < 4; ++c) {
                const float dx = x[j][c] - mean;
                v += dx * dx;
            }
            v += __shfl_xor(v, 1); v += __shfl_xor(v, 2);
            v += __shfl_xor(v, 4); v += __shfl_xor(v, 8);
            const float rsd = rsqrtf(v * (1.0f / 64.0f) + 1e-5f);

            float4 o;
            o.x = (x[j][0] - mean) * rsd * lgq.x + lbq.x;
            o.y = (x[j][1] - mean) * rsd * lgq.y + lbq.y;
            o.z = (x[j][2] - mean) * rsd * lgq.z + lbq.z;
            o.w = (x[j][3] - mean) * rsd * lgq.w + lbq.w;
            *reinterpret_cast<float4*>(out + (size_t)(ebase + 4 * j + g) * 64 + 4 * l15) = o;
        }
    }
}

// ---------------- Node kernel: 3 stacked GVPs (unchanged) ----------------
template <int UOUT, bool SIG>
__device__ __forceinline__ void gvp_step(
    float* __restrict__ s, float* __restrict__ vv,
    const float* __restrict__ Wh, const float* __restrict__ Wu,
    const float* __restrict__ Ws, const float* __restrict__ bs,
    float (*cat)[NBLK], const int tid)
{
    #pragma unroll
    for (int j = 0; j < 64; ++j) cat[j][tid] = s[j];

    float vu[UOUT * 3];
    #pragma unroll
    for (int i = 0; i < UOUT * 3; ++i) vu[i] = 0.0f;

    for (int h = 0; h < V_CH; ++h) {
        float t0 = 0.0f, t1 = 0.0f, t2 = 0.0f;
        #pragma unroll
        for (int vi = 0; vi < V_CH; ++vi) {
            const float wv = Wh[vi * V_CH + h];
            t0 = fmaf(vv[vi * 3 + 0], wv, t0);
            t1 = fmaf(vv[vi * 3 + 1], wv, t1);
            t2 = fmaf(vv[vi * 3 + 2], wv, t2);
        }
        cat[64 + h][tid] = sqrtf(t0 * t0 + t1 * t1 + t2 * t2 + 1e-8f);
        #pragma unroll
        for (int u = 0; u < UOUT; ++u) {
            const float wu = Wu[h * UOUT + u];
            vu[u * 3 + 0] = fmaf(t0, wu, vu[u * 3 + 0]);
            vu[u * 3 + 1] = fmaf(t1, wu, vu[u * 3 + 1]);
            vu[u * 3 + 2] = fmaf(t2, wu, vu[u * 3 + 2]);
        }
    }

    float acc[64];
    #pragma unroll
    for (int j = 0; j < 64; ++j) acc[j] = bs[j];
    #pragma unroll 2
    for (int k = 0; k < 64 + V_CH; ++k) {
        const float hk = cat[k][tid];
        const float* w = Ws + (size_t)k * 64;
        #pragma unroll
        for (int j = 0; j < 64; ++j) acc[j] = fmaf(hk, w[j], acc[j]);
    }
    #pragma unroll
    for (int j = 0; j < 64; ++j) s[j] = silu_f(acc[j]);

    #pragma unroll
    for (int u = 0; u < UOUT; ++u) {
        const float a = vu[u * 3 + 0];
        const float b = vu[u * 3 + 1];
        const float c = vu[u * 3 + 2];
        const float vn = sqrtf(a * a + b * b + c * c + 1e-8f);
        const float gt = SIG ? (1.0f / (1.0f + __expf(-vn))) : vn;
        vv[u * 3 + 0] = gt * a;
        vv[u * 3 + 1] = gt * b;
        vv[u * 3 + 2] = gt * c;
    }
}

__global__ __launch_bounds__(NBLK, 2) void node_kernel(
    const float* __restrict__ ns, const float* __restrict__ pos,
    const float* __restrict__ vec,
    const float* __restrict__ Wh0, const float* __restrict__ Wu0,
    const float* __restrict__ Ws0, const float* __restrict__ bs0,
    const float* __restrict__ Wh1, const float* __restrict__ Wu1,
    const float* __restrict__ Ws1, const float* __restrict__ bs1,
    const float* __restrict__ Wh2, const float* __restrict__ Wu2,
    const float* __restrict__ Ws2, const float* __restrict__ bs2,
    float* __restrict__ outpos)
{
    __shared__ float cat[64 + V_CH][NBLK];
    const int tid = threadIdx.x;
    const int n = blockIdx.x * NBLK + tid;
    const bool active = (n < N_NODES);
    const int nc = active ? n : 0;

    float s[64];
    {
        const float* p = ns + (size_t)nc * S_DIM;
        #pragma unroll
        for (int i = 0; i < 16; ++i) {
            float4 v4 = *reinterpret_cast<const float4*>(p + 4 * i);
            s[4 * i] = v4.x; s[4 * i + 1] = v4.y; s[4 * i + 2] = v4.z; s[4 * i + 3] = v4.w;
        }
    }
    float vv[48];
    {
        const float* p = vec + (size_t)nc * (V_CH * 3);
        #pragma unroll
        for (int i = 0; i < 12; ++i) {
            float4 v4 = *reinterpret_cast<const float4*>(p + 4 * i);
            vv[4 * i] = v4.x; vv[4 * i + 1] = v4.y; vv[4 * i + 2] = v4.z; vv[4 * i + 3] = v4.w;
        }
    }

    gvp_step<V_CH, true>(s, vv, Wh0, Wu0, Ws0, bs0, cat, tid);
    gvp_step<V_CH, true>(s, vv, Wh1, Wu1, Ws1, bs1, cat, tid);
    gvp_step<1, false>(s, vv, Wh2, Wu2, Ws2, bs2, cat, tid);

    if (active) {
        outpos[(size_t)n * 3 + 0] = pos[(size_t)n * 3 + 0] + vv[0];
        outpos[(size_t)n * 3 + 1] = pos[(size_t)n * 3 + 1] + vv[1];
        outpos[(size_t)n * 3 + 2] = pos[(size_t)n * 3 + 2] + vv[2];
    }
}

extern "C" void kernel_launch(void* const* d_in, const int* in_sizes, int n_in,
                              void* d_out, int out_size, void* d_ws, size_t ws_size,
                              hipStream_t stream) {
    const float* ns  = (const float*)d_in[0];
    const float* pos = (const float*)d_in[1];
    const float* vec = (const float*)d_in[2];
    const float* ef  = (const float*)d_in[3];
    const float* dd  = (const float*)d_in[4];
    const int*   src = (const int*)d_in[5];
    const int*   dst = (const int*)d_in[6];
    const float* W1  = (const float*)d_in[7];
    const float* b1  = (const float*)d_in[8];
    const float* W2  = (const float*)d_in[9];
    const float* b2  = (const float*)d_in[10];
    const float* lng = (const float*)d_in[11];
    const float* lnb = (const float*)d_in[12];
    const float* Wh0 = (const float*)d_in[13];
    const float* Wu0 = (const float*)d_in[14];
    const float* Ws0 = (const float*)d_in[15];
    const float* bs0 = (const float*)d_in[16];
    const float* Wh1 = (const float*)d_in[17];
    const float* Wu1 = (const float*)d_in[18];
    const float* Ws1 = (const float*)d_in[19];
    const float* bs1 = (const float*)d_in[20];
    const float* Wh2 = (const float*)d_in[21];
    const float* Wu2 = (const float*)d_in[22];
    const float* Ws2 = (const float*)d_in[23];
    const float* bs2 = (const float*)d_in[24];

    float* out     = (float*)d_out;
    float* out_pos = out + (size_t)N_EDGES * F_DIM;

    edge_kernel<<<EDGE_GRID, 256, 0, stream>>>(
        ns, ef, dd, src, dst, W1, b1, W2, b2, lng, lnb, out);
    node_kernel<<<(N_NODES + NBLK - 1) / NBLK, NBLK, 0, stream>>>(
        ns, pos, vec, Wh0, Wu0, Ws0, bs0, Wh1, Wu1, Ws1, bs1, Wh2, Wu2, Ws2, bs2, out_pos);
}

// Round 8
// 309.841 us; speedup vs baseline: 1.5843x; 1.5843x over previous
//
#include <hip/hip_runtime.h>
#include <hip/hip_bf16.h>

#define N_NODES 100000
#define N_EDGES 1000000
#define S_DIM 64
#define F_DIM 64
#define RBF_DIM 16
#define V_CH 16

typedef __attribute__((ext_vector_type(4))) float f32x4;
typedef __attribute__((ext_vector_type(8))) short bf16x8;

#define NBLK 128
#define TPW 5            // tiles per wave
#define EDGE_GRID 3125   // 3125 * 4 waves * 5 tiles * 16 edges = 1,000,000 exactly

// scheduling fence: pins LDS producer/consumer order WITHOUT a memory clobber
// (memory clobbers pin spilled locals to scratch -- the R7 regression)
#define LDS_FENCE() __builtin_amdgcn_sched_barrier(0)

__device__ __forceinline__ float silu_f(float x) {
    return x * (1.0f / (1.0f + __expf(-x)));
}

__device__ __forceinline__ ushort f2bf(float x) {
    union { __hip_bfloat16 b; ushort u; } c;
    c.b = __float2bfloat16(x);
    return c.u;
}

__device__ __forceinline__ float4 ld4(const float* p) {
    return *reinterpret_cast<const float4*>(p);
}

__device__ __forceinline__ bf16x8 pack8(float4 u, float4 v) {
    bf16x8 r;
    r[0] = (short)f2bf(u.x); r[1] = (short)f2bf(u.y);
    r[2] = (short)f2bf(u.z); r[3] = (short)f2bf(u.w);
    r[4] = (short)f2bf(v.x); r[5] = (short)f2bf(v.y);
    r[6] = (short)f2bf(v.z); r[7] = (short)f2bf(v.w);
    return r;
}

struct Raw { float4 v[14]; };

// ---------------- Edge kernel (MFMA bf16; 3 blocks/CU; shared f32 LDS scratch) --------------
// Per wave: 16-edge x 64-out tile. A-frag: row=lane&15, k=(lane>>4)*8+j.
// C/D: col=lane&15 (+16*nn), row=4*(lane>>4)+reg  [m89-verified layout].
__global__ __launch_bounds__(256, 3) void edge_kernel(
    const float* __restrict__ ns, const float* __restrict__ ef,
    const float* __restrict__ dd, const int* __restrict__ src,
    const int* __restrict__ dst, const float* __restrict__ W1,
    const float* __restrict__ b1, const float* __restrict__ W2,
    const float* __restrict__ b2, const float* __restrict__ lng,
    const float* __restrict__ lnb, float* __restrict__ out)
{
    __shared__ __align__(16) ushort b1f[7][4][64][8];   // 28672 B (W1 frags, write-once)
    __shared__ __align__(16) ushort b2f[2][4][64][8];   //  8192 B (W2 frags, write-once)
    __shared__ __align__(4)  float  hb[4][16][65];      // 16640 B (per-wave scratch, both round trips)
    // total 53504 B -> 3 blocks/CU (stays under the ~53.5KB threshold incl. runtime reserve)

    const int tid  = threadIdx.x;
    const int lane = tid & 63;
    const int wid  = tid >> 6;
    const int l15  = lane & 15;
    const int g    = lane >> 4;

    // ---- one-time W1/W2 swizzle to LDS (bf16x8 both sides; sealed by syncthreads) ----
    {
        const int fl  = tid & 63;
        const int fnn = tid >> 6;
        const int col = 16 * fnn + (fl & 15);
        const int krow = (fl >> 4) << 3;
        #pragma unroll
        for (int kk = 0; kk < 7; ++kk) {
            const int k0 = 32 * kk + krow;
            bf16x8 w;
            #pragma unroll
            for (int j = 0; j < 8; ++j) {
                const int k = k0 + j;
                w[j] = (k < 208) ? (short)f2bf(W1[k * 64 + col]) : (short)0;
            }
            *reinterpret_cast<bf16x8*>(&b1f[kk][fnn][fl][0]) = w;
        }
        #pragma unroll
        for (int kk = 0; kk < 2; ++kk) {
            const int k0 = 32 * kk + krow;
            bf16x8 w;
            #pragma unroll
            for (int j = 0; j < 8; ++j) w[j] = (short)f2bf(W2[(k0 + j) * 64 + col]);
            *reinterpret_cast<bf16x8*>(&b2f[kk][fnn][fl][0]) = w;
        }
    }
    __syncthreads();

    float b1c[4], b2c[4];
    #pragma unroll
    for (int nn = 0; nn < 4; ++nn) {
        b1c[nn] = b1[16 * nn + l15];
        b2c[nn] = b2[16 * nn + l15];
    }
    const float4 lgq = ld4(lng + 4 * l15);   // LN gamma/beta in store layout (cols 4*l15..+3)
    const float4 lbq = ld4(lnb + 4 * l15);

    const int wtile0 = (blockIdx.x * 4 + wid) * TPW;

    int sis[TPW], dis[TPW];
    #pragma unroll
    for (int t = 0; t < TPW; ++t) {
        const int erow = (wtile0 + t) * 16 + l15;
        sis[t] = src[erow];
        dis[t] = dst[erow];
    }

    float (*hbw)[65] = hb[wid];

    auto load_raw = [&](Raw& r, int t) {
        const int erow = (wtile0 + t) * 16 + l15;
        const float* ps = ns + (size_t)sis[t] * 64 + 8 * g;
        const float* pd = ns + (size_t)dis[t] * 64 + 8 * g;
        const float* pe = ef + (size_t)erow * 64 + 8 * g;
        const float* pr = dd + (size_t)erow * 16 + 8 * g;
        r.v[0] = ld4(ps);       r.v[1] = ld4(ps + 4);
        r.v[2] = ld4(ps + 32);  r.v[3] = ld4(ps + 36);
        r.v[4] = ld4(pd);       r.v[5] = ld4(pd + 4);
        r.v[6] = ld4(pd + 32);  r.v[7] = ld4(pd + 36);
        r.v[8] = ld4(pe);       r.v[9] = ld4(pe + 4);
        r.v[10] = ld4(pe + 32); r.v[11] = ld4(pe + 36);
        if (g < 2) { r.v[12] = ld4(pr); r.v[13] = ld4(pr + 4); }
        else { r.v[12] = make_float4(0.f,0.f,0.f,0.f); r.v[13] = make_float4(0.f,0.f,0.f,0.f); }
    };

    Raw r;
    load_raw(r, 0);

    #pragma unroll
    for (int t = 0; t < TPW; ++t) {
        const int ebase = (wtile0 + t) * 16;

        // ---- pack A-frags (consumes r; r is dead afterwards) ----
        bf16x8 a0 = pack8(r.v[0], r.v[1]);
        bf16x8 a1 = pack8(r.v[2], r.v[3]);
        bf16x8 a2f = pack8(r.v[4], r.v[5]);
        bf16x8 a3 = pack8(r.v[6], r.v[7]);
        bf16x8 a4 = pack8(r.v[8], r.v[9]);
        bf16x8 a5 = pack8(r.v[10], r.v[11]);
        bf16x8 a6 = pack8(r.v[12], r.v[13]);

        // ---- issue next tile's loads now; fence pins them ahead of the MFMA block ----
        if (t < TPW - 1) load_raw(r, t + 1);
        LDS_FENCE();

        // ---- layer 1: frags from LDS (write-once array, no hazard) ----
        f32x4 acc[4];
        #pragma unroll
        for (int nn = 0; nn < 4; ++nn) acc[nn] = (f32x4){0.f, 0.f, 0.f, 0.f};
        #pragma unroll
        for (int nn = 0; nn < 4; ++nn) {
            acc[nn] = __builtin_amdgcn_mfma_f32_16x16x32_bf16(a0, *reinterpret_cast<const bf16x8*>(&b1f[0][nn][lane][0]), acc[nn], 0, 0, 0);
            acc[nn] = __builtin_amdgcn_mfma_f32_16x16x32_bf16(a1, *reinterpret_cast<const bf16x8*>(&b1f[1][nn][lane][0]), acc[nn], 0, 0, 0);
            acc[nn] = __builtin_amdgcn_mfma_f32_16x16x32_bf16(a2f, *reinterpret_cast<const bf16x8*>(&b1f[2][nn][lane][0]), acc[nn], 0, 0, 0);
            acc[nn] = __builtin_amdgcn_mfma_f32_16x16x32_bf16(a3, *reinterpret_cast<const bf16x8*>(&b1f[3][nn][lane][0]), acc[nn], 0, 0, 0);
            acc[nn] = __builtin_amdgcn_mfma_f32_16x16x32_bf16(a4, *reinterpret_cast<const bf16x8*>(&b1f[4][nn][lane][0]), acc[nn], 0, 0, 0);
            acc[nn] = __builtin_amdgcn_mfma_f32_16x16x32_bf16(a5, *reinterpret_cast<const bf16x8*>(&b1f[5][nn][lane][0]), acc[nn], 0, 0, 0);
            acc[nn] = __builtin_amdgcn_mfma_f32_16x16x32_bf16(a6, *reinterpret_cast<const bf16x8*>(&b1f[6][nn][lane][0]), acc[nn], 0, 0, 0);
        }

        // ---- round trip 1 (shared hb, f32): h2 C-layout -> A-layout ----
        LDS_FENCE();   // WAR vs previous tile's round-trip-2 reads
        #pragma unroll
        for (int nn = 0; nn < 4; ++nn)
            #pragma unroll
            for (int rr = 0; rr < 4; ++rr)
                hbw[4 * g + rr][16 * nn + l15] = silu_f(acc[nn][rr] + b1c[nn]);
        LDS_FENCE();   // RAW
        bf16x8 q0, q1;
        #pragma unroll
        for (int j = 0; j < 8; ++j) {
            q0[j] = (short)f2bf(hbw[l15][8 * g + j]);
            q1[j] = (short)f2bf(hbw[l15][32 + 8 * g + j]);
        }

        // ---- layer 2 (weights from LDS, write-once array) ----
        f32x4 acc2[4];
        #pragma unroll
        for (int nn = 0; nn < 4; ++nn) acc2[nn] = (f32x4){0.f, 0.f, 0.f, 0.f};
        #pragma unroll
        for (int nn = 0; nn < 4; ++nn) {
            acc2[nn] = __builtin_amdgcn_mfma_f32_16x16x32_bf16(q0, *reinterpret_cast<const bf16x8*>(&b2f[0][nn][lane][0]), acc2[nn], 0, 0, 0);
            acc2[nn] = __builtin_amdgcn_mfma_f32_16x16x32_bf16(q1, *reinterpret_cast<const bf16x8*>(&b2f[1][nn][lane][0]), acc2[nn], 0, 0, 0);
        }

        // ---- round trip 2 (shared hb, f32): silu(acc2)+b2 C-layout -> row-quad layout ----
        LDS_FENCE();   // WAR vs round-trip-1 reads above
        #pragma unroll
        for (int nn = 0; nn < 4; ++nn)
            #pragma unroll
            for (int rr = 0; rr < 4; ++rr)
                hbw[4 * g + rr][16 * nn + l15] = silu_f(acc2[nn][rr] + b2c[nn]);
        LDS_FENCE();   // RAW

        // lane now owns rows (4j+g), cols 4*l15..4*l15+3
        float x[4][4];
        #pragma unroll
        for (int j = 0; j < 4; ++j) {
            const float* hr = &hbw[4 * j + g][4 * l15];
            const float4 e = ld4(ef + (size_t)(ebase + 4 * j + g) * 64 + 4 * l15);  // L1/L2-hot
            x[j][0] = hr[0] + e.x;
            x[j][1] = hr[1] + e.y;
            x[j][2] = hr[2] + e.z;
            x[j][3] = hr[3] + e.w;
        }

        // ---- layernorm: row = 16-lane group sharing g ----
        #pragma unroll
        for (int j = 0; j < 4; ++j) {
            float s = x[j][0] + x[j][1] + x[j][2] + x[j][3];
            s += __shfl_xor(s, 1); s += __shfl_xor(s, 2);
            s += __shfl_xor(s, 4); s += __shfl_xor(s, 8);
            const float mean = s * (1.0f / 64.0f);
            float v = 0.f;
            #pragma unroll
            for (int c = 0; c < 4; ++c) {
                const float dx = x[j][c] - mean;
                v += dx * dx;
            }
            v += __shfl_xor(v, 1); v += __shfl_xor(v, 2);
            v += __shfl_xor(v, 4); v += __shfl_xor(v, 8);
            const float rsd = rsqrtf(v * (1.0f / 64.0f) + 1e-5f);

            float4 o;
            o.x = (x[j][0] - mean) * rsd * lgq.x + lbq.x;
            o.y = (x[j][1] - mean) * rsd * lgq.y + lbq.y;
            o.z = (x[j][2] - mean) * rsd * lgq.z + lbq.z;
            o.w = (x[j][3] - mean) * rsd * lgq.w + lbq.w;
            *reinterpret_cast<float4*>(out + (size_t)(ebase + 4 * j + g) * 64 + 4 * l15) = o;
        }
        LDS_FENCE();   // seal transpose reads before next tile's rt1 writes
    }
}

// ---------------- Node kernel: 3 stacked GVPs (unchanged) ----------------
template <int UOUT, bool SIG>
__device__ __forceinline__ void gvp_step(
    float* __restrict__ s, float* __restrict__ vv,
    const float* __restrict__ Wh, const float* __restrict__ Wu,
    const float* __restrict__ Ws, const float* __restrict__ bs,
    float (*cat)[NBLK], const int tid)
{
    #pragma unroll
    for (int j = 0; j < 64; ++j) cat[j][tid] = s[j];

    float vu[UOUT * 3];
    #pragma unroll
    for (int i = 0; i < UOUT * 3; ++i) vu[i] = 0.0f;

    for (int h = 0; h < V_CH; ++h) {
        float t0 = 0.0f, t1 = 0.0f, t2 = 0.0f;
        #pragma unroll
        for (int vi = 0; vi < V_CH; ++vi) {
            const float wv = Wh[vi * V_CH + h];
            t0 = fmaf(vv[vi * 3 + 0], wv, t0);
            t1 = fmaf(vv[vi * 3 + 1], wv, t1);
            t2 = fmaf(vv[vi * 3 + 2], wv, t2);
        }
        cat[64 + h][tid] = sqrtf(t0 * t0 + t1 * t1 + t2 * t2 + 1e-8f);
        #pragma unroll
        for (int u = 0; u < UOUT; ++u) {
            const float wu = Wu[h * UOUT + u];
            vu[u * 3 + 0] = fmaf(t0, wu, vu[u * 3 + 0]);
            vu[u * 3 + 1] = fmaf(t1, wu, vu[u * 3 + 1]);
            vu[u * 3 + 2] = fmaf(t2, wu, vu[u * 3 + 2]);
        }
    }

    float acc[64];
    #pragma unroll
    for (int j = 0; j < 64; ++j) acc[j] = bs[j];
    #pragma unroll 2
    for (int k = 0; k < 64 + V_CH; ++k) {
        const float hk = cat[k][tid];
        const float* w = Ws + (size_t)k * 64;
        #pragma unroll
        for (int j = 0; j < 64; ++j) acc[j] = fmaf(hk, w[j], acc[j]);
    }
    #pragma unroll
    for (int j = 0; j < 64; ++j) s[j] = silu_f(acc[j]);

    #pragma unroll
    for (int u = 0; u < UOUT; ++u) {
        const float a = vu[u * 3 + 0];
        const float b = vu[u * 3 + 1];
        const float c = vu[u * 3 + 2];
        const float vn = sqrtf(a * a + b * b + c * c + 1e-8f);
        const float gt = SIG ? (1.0f / (1.0f + __expf(-vn))) : vn;
        vv[u * 3 + 0] = gt * a;
        vv[u * 3 + 1] = gt * b;
        vv[u * 3 + 2] = gt * c;
    }
}

__global__ __launch_bounds__(NBLK, 2) void node_kernel(
    const float* __restrict__ ns, const float* __restrict__ pos,
    const float* __restrict__ vec,
    const float* __restrict__ Wh0, const float* __restrict__ Wu0,
    const float* __restrict__ Ws0, const float* __restrict__ bs0,
    const float* __restrict__ Wh1, const float* __restrict__ Wu1,
    const float* __restrict__ Ws1, const float* __restrict__ bs1,
    const float* __restrict__ Wh2, const float* __restrict__ Wu2,
    const float* __restrict__ Ws2, const float* __restrict__ bs2,
    float* __restrict__ outpos)
{
    __shared__ float cat[64 + V_CH][NBLK];
    const int tid = threadIdx.x;
    const int n = blockIdx.x * NBLK + tid;
    const bool active = (n < N_NODES);
    const int nc = active ? n : 0;

    float s[64];
    {
        const float* p = ns + (size_t)nc * S_DIM;
        #pragma unroll
        for (int i = 0; i < 16; ++i) {
            float4 v4 = *reinterpret_cast<const float4*>(p + 4 * i);
            s[4 * i] = v4.x; s[4 * i + 1] = v4.y; s[4 * i + 2] = v4.z; s[4 * i + 3] = v4.w;
        }
    }
    float vv[48];
    {
        const float* p = vec + (size_t)nc * (V_CH * 3);
        #pragma unroll
        for (int i = 0; i < 12; ++i) {
            float4 v4 = *reinterpret_cast<const float4*>(p + 4 * i);
            vv[4 * i] = v4.x; vv[4 * i + 1] = v4.y; vv[4 * i + 2] = v4.z; vv[4 * i + 3] = v4.w;
        }
    }

    gvp_step<V_CH, true>(s, vv, Wh0, Wu0, Ws0, bs0, cat, tid);
    gvp_step<V_CH, true>(s, vv, Wh1, Wu1, Ws1, bs1, cat, tid);
    gvp_step<1, false>(s, vv, Wh2, Wu2, Ws2, bs2, cat, tid);

    if (active) {
        outpos[(size_t)n * 3 + 0] = pos[(size_t)n * 3 + 0] + vv[0];
        outpos[(size_t)n * 3 + 1] = pos[(size_t)n * 3 + 1] + vv[1];
        outpos[(size_t)n * 3 + 2] = pos[(size_t)n * 3 + 2] + vv[2];
    }
}

extern "C" void kernel_launch(void* const* d_in, const int* in_sizes, int n_in,
                              void* d_out, int out_size, void* d_ws, size_t ws_size,
                              hipStream_t stream) {
    const float* ns  = (const float*)d_in[0];
    const float* pos = (const float*)d_in[1];
    const float* vec = (const float*)d_in[2];
    const float* ef  = (const float*)d_in[3];
    const float* dd  = (const float*)d_in[4];
    const int*   src = (const int*)d_in[5];
    const int*   dst = (const int*)d_in[6];
    const float* W1  = (const float*)d_in[7];
    const float* b1  = (const float*)d_in[8];
    const float* W2  = (const float*)d_in[9];
    const float* b2  = (const float*)d_in[10];
    const float* lng = (const float*)d_in[11];
    const float* lnb = (const float*)d_in[12];
    const float* Wh0 = (const float*)d_in[13];
    const float* Wu0 = (const float*)d_in[14];
    const float* Ws0 = (const float*)d_in[15];
    const float* bs0 = (const float*)d_in[16];
    const float* Wh1 = (const float*)d_in[17];
    const float* Wu1 = (const float*)d_in[18];
    const float* Ws1 = (const float*)d_in[19];
    const float* bs1 = (const float*)d_in[20];
    const float* Wh2 = (const float*)d_in[21];
    const float* Wu2 = (const float*)d_in[22];
    const float* Ws2 = (const float*)d_in[23];
    const float* bs2 = (const float*)d_in[24];

    float* out     = (float*)d_out;
    float* out_pos = out + (size_t)N_EDGES * F_DIM;

    edge_kernel<<<EDGE_GRID, 256, 0, stream>>>(
        ns, ef, dd, src, dst, W1, b1, W2, b2, lng, lnb, out);
    node_kernel<<<(N_NODES + NBLK - 1) / NBLK, NBLK, 0, stream>>>(
        ns, pos, vec, Wh0, Wu0, Ws0, bs0, Wh1, Wu1, Ws1, bs1, Wh2, Wu2, Ws2, bs2, out_pos);
}